// Round 5
// baseline (621.685 us; speedup 1.0000x reference)
//
#include <hip/hip_runtime.h>

// MoE top-2 of 8 experts. T=4096, H=1024, F=4096.
// router -> scan(256-aligned regions) -> gather(x->bf16 + inv_map) ->
// W transpose/cvt bf16 (BT layout) -> 8-phase grouped GEMM1(relu) ->
// 8-phase grouped GEMM2 (K-split x2) with fused atomic combine into out.
#define T_TOK 4096
#define H_DIM 1024
#define F_DIM 4096
#define E_NUM 8
#define R_TOT 8192
#define R_CAP 10240       // 256-aligned regions: max 40 tiles

typedef short bf16x8 __attribute__((ext_vector_type(8)));
typedef float f32x4 __attribute__((ext_vector_type(4)));

__device__ inline unsigned short f2bf(float f) {   // RNE f32 -> bf16
  unsigned int u = __builtin_bit_cast(unsigned int, f);
  return (unsigned short)((u + 0x7FFFu + ((u >> 16) & 1u)) >> 16);
}

__device__ inline void async16(const void* g, void* l) {
  __builtin_amdgcn_global_load_lds((const __attribute__((address_space(1))) void*)g,
                                   (__attribute__((address_space(3))) void*)l, 16, 0, 0);
}

// ---------------- router ------------------------------------------------------
__global__ __launch_bounds__(256) void router_k(
    const float* __restrict__ x, const float* __restrict__ Wr,
    const float* __restrict__ br, int* __restrict__ ctrl,
    int* __restrict__ t2i, float* __restrict__ t2w) {
  int lane = threadIdx.x & 63;
  int wid  = threadIdx.x >> 6;
  int t = blockIdx.x * 4 + wid;
  const float* xr = x + (size_t)t * H_DIM;
  double acc[E_NUM];
#pragma unroll
  for (int e = 0; e < E_NUM; e++) acc[e] = 0.0;
  for (int i = lane; i < H_DIM; i += 64) {
    float xv = xr[i];
    const float* wr = Wr + (size_t)i * E_NUM;
    float4 w0 = *(const float4*)wr;
    float4 w1 = *(const float4*)(wr + 4);
    acc[0] += (double)xv * w0.x; acc[1] += (double)xv * w0.y;
    acc[2] += (double)xv * w0.z; acc[3] += (double)xv * w0.w;
    acc[4] += (double)xv * w1.x; acc[5] += (double)xv * w1.y;
    acc[6] += (double)xv * w1.z; acc[7] += (double)xv * w1.w;
  }
#pragma unroll
  for (int e = 0; e < E_NUM; e++) {
    double v = acc[e];
    for (int off = 32; off > 0; off >>= 1) v += __shfl_down(v, off);
    acc[e] = v;
  }
  if (lane == 0) {
    float l[E_NUM];
#pragma unroll
    for (int e = 0; e < E_NUM; e++) l[e] = (float)acc[e] + br[e];
    int ia = 0; float la = l[0];
#pragma unroll
    for (int e = 1; e < E_NUM; e++) if (l[e] > la) { la = l[e]; ia = e; }
    int ib = -1; float lb = -3.4e38f;
#pragma unroll
    for (int e = 0; e < E_NUM; e++) if (e != ia && l[e] > lb) { lb = l[e]; ib = e; }
    float w0 = 1.f / (1.f + __expf(lb - la));
    float w1 = 1.f - w0;
    t2i[2 * t] = ia; t2i[2 * t + 1] = ib;
    t2w[2 * t] = w0; t2w[2 * t + 1] = w1;
    atomicAdd(&ctrl[ia], 1);
    atomicAdd(&ctrl[ib], 1);
  }
}

// ------- scan: 256-ALIGNED offsets, cursors, row-tile table -------------------
__global__ void scan_k(int* ctrl) {
  if (threadIdx.x != 0) return;
  int off = 0, nt = 0;
  for (int e = 0; e < E_NUM; e++) {
    int c = ctrl[e];
    ctrl[8 + e]  = off;
    ctrl[17 + e] = off;
    int tiles = (c + 255) >> 8;
    for (int j = 0; j < tiles; j++) {
      ctrl[32 + 2 * nt] = e;
      ctrl[33 + 2 * nt] = off + j * 256;
      nt++;
    }
    off += tiles * 256;
  }
  ctrl[16] = off;
  ctrl[25] = nt;
}

// ---------------- gather: x row -> bf16 row; inv_map[row] = token*2+slot ------
__global__ __launch_bounds__(128) void gather_k(
    const float* __restrict__ x, const int* __restrict__ t2i,
    int* __restrict__ ctrl, int* __restrict__ inv_map,
    unsigned short* __restrict__ xg) {
  int bid = blockIdx.x;
  __shared__ int srow;
  if (threadIdx.x == 0) {
    int e = t2i[bid];
    int row = atomicAdd(&ctrl[17 + e], 1);
    inv_map[row] = bid;
    srow = row;
  }
  __syncthreads();
  int row = srow;
  int t = bid >> 1;
  const float* src = x + (size_t)t * H_DIM + threadIdx.x * 8;
  unsigned short* dst = xg + (size_t)row * H_DIM + threadIdx.x * 8;
  float4 v0 = *(const float4*)src;
  float4 v1 = *(const float4*)(src + 4);
  uint4 o;
  o.x = (unsigned int)f2bf(v0.x) | ((unsigned int)f2bf(v0.y) << 16);
  o.y = (unsigned int)f2bf(v0.z) | ((unsigned int)f2bf(v0.w) << 16);
  o.z = (unsigned int)f2bf(v1.x) | ((unsigned int)f2bf(v1.y) << 16);
  o.w = (unsigned int)f2bf(v1.z) | ((unsigned int)f2bf(v1.w) << 16);
  *(uint4*)dst = o;
}

// ---------------- transpose + fp32->bf16: in[E][R][C] -> out[E][C][R] ---------
__global__ __launch_bounds__(256) void transpose_cvt_k(
    const float* __restrict__ in, unsigned short* __restrict__ out, int R, int C) {
  __shared__ unsigned short tile[64][68];
  size_t mat = (size_t)R * C;
  const float* ine = in + (size_t)blockIdx.z * mat;
  unsigned short* oute = out + (size_t)blockIdx.z * mat;
  int c0 = blockIdx.x * 64, r0 = blockIdx.y * 64;
  int tr = threadIdx.x >> 4, tc = threadIdx.x & 15;
#pragma unroll
  for (int p = 0; p < 4; p++) {
    int r = tr + p * 16;
    float4 v = *(const float4*)(ine + (size_t)(r0 + r) * C + c0 + tc * 4);
    tile[r][tc * 4 + 0] = f2bf(v.x);
    tile[r][tc * 4 + 1] = f2bf(v.y);
    tile[r][tc * 4 + 2] = f2bf(v.z);
    tile[r][tc * 4 + 3] = f2bf(v.w);
  }
  __syncthreads();
#pragma unroll
  for (int p = 0; p < 4; p++) {
    int c = tr + p * 16;
    unsigned int u0 = (unsigned int)tile[tc * 4 + 0][c] | ((unsigned int)tile[tc * 4 + 1][c] << 16);
    unsigned int u1 = (unsigned int)tile[tc * 4 + 2][c] | ((unsigned int)tile[tc * 4 + 3][c] << 16);
    uint2 o = make_uint2(u0, u1);
    *(uint2*)(oute + (size_t)(c0 + c) * R + r0 + tc * 4) = o;
  }
}

// =============== 8-phase grouped BT GEMM, 256x256 tile, BK=64, 8 waves ========
// LDS layout (per 32KB tile buffer, A and B identical): row-major [256][64]
// bf16 with XOR-swizzled 16B k-octets:  unit(16B) = row*8 + (koct ^ (row&7)).
// Staging dest linear in tid; global source pre-swizzled within each row's
// 128B line (coalesced).  ds_read_b128 fragments: 2-way bank use (free).
// Phases consume A row-chunks {0,2} (p0,p1) then {1,3} (p2,p3); B whole in p0.
// Staging per tile t: p0 -> A chunks 1,3 of t+1 (next buf); p1 -> B 0,1 of
// t+2 (cur buf, dead after p0); p2 -> B 2,3 of t+2; p3 -> A 0,2 of t+2 (dead
// after p1).  vmcnt(10) end of p1; vmcnt(8) end of p3.  Never 0.
// Plain s_barrier (no sched_barrier fences — m141: order-pinning regresses;
// STG/vmcnt-asm/barrier are all side-effecting so their mutual order holds).
#define BAR() __builtin_amdgcn_s_barrier()

#define STG(gbase, kt, lbuf, c) \
  async16((gbase) + (size_t)((c) * 64 + srcRow) * Kstr + (kt) + srcK8, \
          (lbuf) + (c) * 4096 + tid * 8)

#define LDU(buf, row, koct) \
  (*(const bf16x8*)((buf) + (((row) * 8 + ((koct) ^ ((row) & 7))) * 8)))

#define LDA4(P) \
  const int ar0 = wm * 128 + (P) * 32 + lr; \
  bf16x8 aA = LDU(lAc, ar0, klane); \
  bf16x8 aB = LDU(lAc, ar0, 4 + klane); \
  bf16x8 aC = LDU(lAc, ar0 + 16, klane); \
  bf16x8 aD = LDU(lAc, ar0 + 16, 4 + klane);

#define PHASE_MFMA(M0, M1) \
  __builtin_amdgcn_s_setprio(1); \
  _Pragma("unroll") \
  for (int n = 0; n < 4; n++) { \
    acc[M0][n] = __builtin_amdgcn_mfma_f32_16x16x32_bf16(aA, b[n][0], acc[M0][n], 0, 0, 0); \
    acc[M0][n] = __builtin_amdgcn_mfma_f32_16x16x32_bf16(aB, b[n][1], acc[M0][n], 0, 0, 0); \
    acc[M1][n] = __builtin_amdgcn_mfma_f32_16x16x32_bf16(aC, b[n][0], acc[M1][n], 0, 0, 0); \
    acc[M1][n] = __builtin_amdgcn_mfma_f32_16x16x32_bf16(aD, b[n][1], acc[M1][n], 0, 0, 0); \
  } \
  __builtin_amdgcn_s_setprio(0);

template <bool RELU, bool COMBINE>
__global__ __launch_bounds__(512, 2) void gemm8_k(
    const int* __restrict__ ctrl, const unsigned short* __restrict__ A,
    const unsigned short* __restrict__ Bw, const float* __restrict__ bias,
    void* __restrict__ Cout, const int* __restrict__ inv_map,
    const float* __restrict__ t2w, int Kstr, int N) {
  __shared__ unsigned short lds[65536];   // 128 KiB: A 2x32KB | B 2x32KB
  int rt = blockIdx.y;
  if (rt >= ctrl[25]) return;
  const int e    = ctrl[32 + 2 * rt];
  const int row0 = ctrl[33 + 2 * rt];
  const int NTloc = (Kstr >> 6) / (int)gridDim.z;   // K-split over blockIdx.z
  const int k0 = blockIdx.z * NTloc * 64;
  const bool addb = (blockIdx.z == 0);
  const unsigned short* Ae = A + (size_t)row0 * Kstr + k0;
  const unsigned short* Be = Bw + (size_t)e * ((size_t)N * Kstr)
                             + (size_t)blockIdx.x * 256 * Kstr + k0;
  unsigned short* lA = lds;
  unsigned short* lB = lds + 32768;
  const int tid = threadIdx.x, lane = tid & 63;
  const int wid = tid >> 6, wm = wid >> 2, wn = wid & 3;
  const int lr = lane & 15, klane = lane >> 4;
  const int srcRow = tid >> 3;                         // 0..63 within chunk
  const int srcK8  = ((tid & 7) ^ (srcRow & 7)) * 8;   // pre-swizzled k-octet

  f32x4 acc[8][4];
  f32x4 zero4 = {0.f, 0.f, 0.f, 0.f};
#pragma unroll
  for (int m = 0; m < 8; m++)
#pragma unroll
    for (int n = 0; n < 4; n++) acc[m][n] = zero4;

  // prologue: tile0 full (8), tile1 partial (B0-3, A0, A2)
  {
    STG(Ae, 0, lA, 0); STG(Ae, 0, lA, 1); STG(Ae, 0, lA, 2); STG(Ae, 0, lA, 3);
    STG(Be, 0, lB, 0); STG(Be, 0, lB, 1); STG(Be, 0, lB, 2); STG(Be, 0, lB, 3);
    STG(Be, 64, lB + 16384, 0); STG(Be, 64, lB + 16384, 1);
    STG(Be, 64, lB + 16384, 2); STG(Be, 64, lB + 16384, 3);
    STG(Ae, 64, lA + 16384, 0); STG(Ae, 64, lA + 16384, 2);
    asm volatile("s_waitcnt vmcnt(6)" ::: "memory");
    BAR();
  }

  for (int t = 0; t < NTloc; t++) {
    const int cur = t & 1;
    unsigned short* lAc = lA + cur * 16384;
    unsigned short* lBc = lB + cur * 16384;
    unsigned short* lAn = lA + (cur ^ 1) * 16384;
    const int kt1 = min(t + 1, NTloc - 1) * 64;
    const int kt2 = min(t + 2, NTloc - 1) * 64;
    bf16x8 b[4][2];
    { // ---- phase 0: read B whole + A rows 0-31; stage A chunks 1,3 of t+1
#pragma unroll
      for (int n = 0; n < 4; n++) {
        int brow = wn * 64 + n * 16 + lr;
        b[n][0] = LDU(lBc, brow, klane);
        b[n][1] = LDU(lBc, brow, 4 + klane);
      }
      LDA4(0)
      STG(Ae, kt1, lAn, 1); STG(Ae, kt1, lAn, 3);
      BAR();
      PHASE_MFMA(0, 1)
      BAR();
    }
    { // ---- phase 1: A rows 32-63; stage B chunks 0,1 of t+2; vmcnt(10)
      LDA4(1)
      STG(Be, kt2, lBc, 0); STG(Be, kt2, lBc, 1);
      BAR();
      PHASE_MFMA(2, 3)
      asm volatile("s_waitcnt vmcnt(10)" ::: "memory");
      BAR();
    }
    { // ---- phase 2: A rows 64-95; stage B chunks 2,3 of t+2
      LDA4(2)
      STG(Be, kt2, lBc, 2); STG(Be, kt2, lBc, 3);
      BAR();
      PHASE_MFMA(4, 5)
      BAR();
    }
    { // ---- phase 3: A rows 96-127; stage A chunks 0,2 of t+2; vmcnt(8)
      LDA4(3)
      STG(Ae, kt2, lAc, 0); STG(Ae, kt2, lAc, 2);
      BAR();
      PHASE_MFMA(6, 7)
      asm volatile("s_waitcnt vmcnt(8)" ::: "memory");
      BAR();
    }
  }

  // ---------------- epilogue ---------------------------------------------------
  const int n0 = blockIdx.x * 256;
  const float* be = bias + (size_t)e * N;
  if (COMBINE) {
    float* outp = (float*)Cout;
#pragma unroll
    for (int m = 0; m < 8; m++) {
#pragma unroll
      for (int q = 0; q < 4; q++) {
        int grow = row0 + wm * 128 + m * 16 + (lane >> 4) * 4 + q;
        int inv = inv_map[grow];
        if (inv >= 0) {
          float w = t2w[inv];
          float* orow = outp + (size_t)(inv >> 1) * H_DIM;
#pragma unroll
          for (int n = 0; n < 4; n++) {
            int col = n0 + wn * 64 + n * 16 + lr;
            float v = acc[m][n][q] + (addb ? be[col] : 0.f);
            atomicAdd(orow + col, w * v);
          }
        }
      }
    }
  } else {
    unsigned short* outp = (unsigned short*)Cout;
#pragma unroll
    for (int m = 0; m < 8; m++) {
#pragma unroll
      for (int q = 0; q < 4; q++) {
        size_t ro = (size_t)(row0 + wm * 128 + m * 16 + (lane >> 4) * 4 + q) * N;
#pragma unroll
        for (int n = 0; n < 4; n++) {
          int col = n0 + wn * 64 + n * 16 + lr;
          float v = acc[m][n][q] + be[col];
          if (RELU) v = fmaxf(v, 0.f);
          outp[ro + col] = f2bf(v);
        }
      }
    }
  }
}

extern "C" void kernel_launch(void* const* d_in, const int* in_sizes, int n_in,
                              void* d_out, int out_size, void* d_ws, size_t ws_size,
                              hipStream_t stream) {
  const float* x  = (const float*)d_in[0];
  const float* Wr = (const float*)d_in[1];
  const float* br = (const float*)d_in[2];
  const float* W1 = (const float*)d_in[3];
  const float* b1 = (const float*)d_in[4];
  const float* W2 = (const float*)d_in[5];
  const float* b2 = (const float*)d_in[6];
  float* out = (float*)d_out;

  char* ws = (char*)d_ws;
  int*   ctrl    = (int*)ws;                       // counts/offs/cursors/tile table
  int*   t2i     = (int*)(ws + 4096);
  float* t2w     = (float*)(ws + 4096 + 32768);
  int*   inv_map = (int*)(ws + 4096 + 65536);      // R_CAP ints
  size_t off = (size_t)1 << 20;
  unsigned short* WT1 = (unsigned short*)(ws + off); off += (size_t)E_NUM * F_DIM * H_DIM * 2;
  unsigned short* WT2 = (unsigned short*)(ws + off); off += (size_t)E_NUM * H_DIM * F_DIM * 2;
  unsigned short* xg  = (unsigned short*)(ws + off); off += (size_t)R_CAP * H_DIM * 2;
  unsigned short* hb  = (unsigned short*)(ws + off); off += (size_t)R_CAP * F_DIM * 2;

  if (ws_size < off) {
    hipMemsetAsync(d_out, 0, (size_t)out_size * 4, stream);
    return;
  }

  hipMemsetAsync(ctrl, 0, 4096, stream);
  hipMemsetAsync(inv_map, 0xFF, (size_t)R_CAP * 4, stream);        // -1 = pad row
  hipMemsetAsync(out, 0, (size_t)out_size * 4, stream);            // atomics accumulate
  transpose_cvt_k<<<dim3(F_DIM / 64, H_DIM / 64, E_NUM), 256, 0, stream>>>(W1, WT1, H_DIM, F_DIM);
  transpose_cvt_k<<<dim3(H_DIM / 64, F_DIM / 64, E_NUM), 256, 0, stream>>>(W2, WT2, F_DIM, H_DIM);
  router_k<<<dim3(T_TOK / 4), 256, 0, stream>>>(x, Wr, br, ctrl, t2i, t2w);
  scan_k<<<dim3(1), 64, 0, stream>>>(ctrl);
  gather_k<<<dim3(R_TOT), 128, 0, stream>>>(x, t2i, ctrl, inv_map, xg);
  // GEMM1: hb = relu(xg @ W1 + b1), bf16   [rows x F]
  gemm8_k<true, false><<<dim3(F_DIM / 256, 40, 1), 512, 0, stream>>>(
      ctrl, xg, WT1, b1, hb, nullptr, nullptr, H_DIM, F_DIM);
  // GEMM2 + fused combine (K-split x2): out[tok] += w * (hb @ W2 [+ b2])
  gemm8_k<false, true><<<dim3(H_DIM / 256, 40, 2), 512, 0, stream>>>(
      ctrl, hb, WT2, b2, out, inv_map, t2w, F_DIM, H_DIM);
}

// Round 6
// 504.106 us; speedup vs baseline: 1.2332x; 1.2332x over previous
//
#include <hip/hip_runtime.h>

// MoE top-2 of 8 experts. T=4096, H=1024, F=4096.
// router -> scan(256-aligned regions) -> gather(x->bf16 + row_map) ->
// W transpose/cvt bf16 (BT layout, conflict-free fp32 tile) ->
// 8-phase grouped GEMM1(relu, bf16 out) -> 8-phase grouped GEMM2 (f32 out) ->
// deterministic combine gather (no atomics anywhere).
#define T_TOK 4096
#define H_DIM 1024
#define F_DIM 4096
#define E_NUM 8
#define R_TOT 8192
#define R_CAP 9984        // 256-aligned regions: max 39 tiles = 9984 rows

typedef short bf16x8 __attribute__((ext_vector_type(8)));
typedef float f32x4 __attribute__((ext_vector_type(4)));

__device__ inline unsigned short f2bf(float f) {   // RNE f32 -> bf16
  unsigned int u = __builtin_bit_cast(unsigned int, f);
  return (unsigned short)((u + 0x7FFFu + ((u >> 16) & 1u)) >> 16);
}

__device__ inline void async16(const void* g, void* l) {
  __builtin_amdgcn_global_load_lds((const __attribute__((address_space(1))) void*)g,
                                   (__attribute__((address_space(3))) void*)l, 16, 0, 0);
}

// ---------------- router ------------------------------------------------------
__global__ __launch_bounds__(256) void router_k(
    const float* __restrict__ x, const float* __restrict__ Wr,
    const float* __restrict__ br, int* __restrict__ ctrl,
    int* __restrict__ t2i, float* __restrict__ t2w) {
  int lane = threadIdx.x & 63;
  int wid  = threadIdx.x >> 6;
  int t = blockIdx.x * 4 + wid;
  const float* xr = x + (size_t)t * H_DIM;
  double acc[E_NUM];
#pragma unroll
  for (int e = 0; e < E_NUM; e++) acc[e] = 0.0;
  for (int i = lane; i < H_DIM; i += 64) {
    float xv = xr[i];
    const float* wr = Wr + (size_t)i * E_NUM;
    float4 w0 = *(const float4*)wr;
    float4 w1 = *(const float4*)(wr + 4);
    acc[0] += (double)xv * w0.x; acc[1] += (double)xv * w0.y;
    acc[2] += (double)xv * w0.z; acc[3] += (double)xv * w0.w;
    acc[4] += (double)xv * w1.x; acc[5] += (double)xv * w1.y;
    acc[6] += (double)xv * w1.z; acc[7] += (double)xv * w1.w;
  }
#pragma unroll
  for (int e = 0; e < E_NUM; e++) {
    double v = acc[e];
    for (int off = 32; off > 0; off >>= 1) v += __shfl_down(v, off);
    acc[e] = v;
  }
  if (lane == 0) {
    float l[E_NUM];
#pragma unroll
    for (int e = 0; e < E_NUM; e++) l[e] = (float)acc[e] + br[e];
    int ia = 0; float la = l[0];
#pragma unroll
    for (int e = 1; e < E_NUM; e++) if (l[e] > la) { la = l[e]; ia = e; }
    int ib = -1; float lb = -3.4e38f;
#pragma unroll
    for (int e = 0; e < E_NUM; e++) if (e != ia && l[e] > lb) { lb = l[e]; ib = e; }
    float w0 = 1.f / (1.f + __expf(lb - la));
    float w1 = 1.f - w0;
    t2i[2 * t] = ia; t2i[2 * t + 1] = ib;
    t2w[2 * t] = w0; t2w[2 * t + 1] = w1;
    atomicAdd(&ctrl[ia], 1);
    atomicAdd(&ctrl[ib], 1);
  }
}

// ------- scan: 256-ALIGNED offsets, cursors, row-tile table -------------------
__global__ void scan_k(int* ctrl) {
  if (threadIdx.x != 0) return;
  int off = 0, nt = 0;
  for (int e = 0; e < E_NUM; e++) {
    int c = ctrl[e];
    ctrl[8 + e]  = off;
    ctrl[17 + e] = off;
    int tiles = (c + 255) >> 8;
    for (int j = 0; j < tiles; j++) {
      ctrl[32 + 2 * nt] = e;
      ctrl[33 + 2 * nt] = off + j * 256;
      nt++;
    }
    off += tiles * 256;
  }
  ctrl[16] = off;
  ctrl[25] = nt;
}

// ---------------- gather: x row -> bf16 row; row_map[token*2+slot] = row ------
__global__ __launch_bounds__(128) void gather_k(
    const float* __restrict__ x, const int* __restrict__ t2i,
    int* __restrict__ ctrl, int* __restrict__ row_map,
    unsigned short* __restrict__ xg) {
  int bid = blockIdx.x;
  __shared__ int srow;
  if (threadIdx.x == 0) {
    int e = t2i[bid];
    int row = atomicAdd(&ctrl[17 + e], 1);
    row_map[bid] = row;
    srow = row;
  }
  __syncthreads();
  int row = srow;
  int t = bid >> 1;
  const float* src = x + (size_t)t * H_DIM + threadIdx.x * 8;
  unsigned short* dst = xg + (size_t)row * H_DIM + threadIdx.x * 8;
  float4 v0 = *(const float4*)src;
  float4 v1 = *(const float4*)(src + 4);
  uint4 o;
  o.x = (unsigned int)f2bf(v0.x) | ((unsigned int)f2bf(v0.y) << 16);
  o.y = (unsigned int)f2bf(v0.z) | ((unsigned int)f2bf(v0.w) << 16);
  o.z = (unsigned int)f2bf(v1.x) | ((unsigned int)f2bf(v1.y) << 16);
  o.w = (unsigned int)f2bf(v1.z) | ((unsigned int)f2bf(v1.w) << 16);
  *(uint4*)dst = o;
}

// ------- transpose + fp32->bf16: in[E][R][C] -> out[E][C][R], fp32 LDS tile ---
// tile[64][65] floats: both passes are 2-way bank use (free). Loads: 4 rows x
// 256B per wave; stores: 4 rows x 128B per wave (coalesced).
__global__ __launch_bounds__(256) void transpose_cvt_k(
    const float* __restrict__ in, unsigned short* __restrict__ out, int R, int C) {
  __shared__ float tile[64][65];
  size_t mat = (size_t)R * C;
  const float* ine = in + (size_t)blockIdx.z * mat;
  unsigned short* oute = out + (size_t)blockIdx.z * mat;
  int c0 = blockIdx.x * 64, r0 = blockIdx.y * 64;
  int tr = threadIdx.x >> 4, tc = threadIdx.x & 15;
#pragma unroll
  for (int p = 0; p < 4; p++) {
    int r = tr + p * 16;
    float4 v = *(const float4*)(ine + (size_t)(r0 + r) * C + c0 + tc * 4);
    tile[r][tc * 4 + 0] = v.x; tile[r][tc * 4 + 1] = v.y;
    tile[r][tc * 4 + 2] = v.z; tile[r][tc * 4 + 3] = v.w;
  }
  __syncthreads();
#pragma unroll
  for (int p = 0; p < 4; p++) {
    int c = tr + p * 16;
    unsigned int u0 = (unsigned int)f2bf(tile[tc * 4 + 0][c]) |
                      ((unsigned int)f2bf(tile[tc * 4 + 1][c]) << 16);
    unsigned int u1 = (unsigned int)f2bf(tile[tc * 4 + 2][c]) |
                      ((unsigned int)f2bf(tile[tc * 4 + 3][c]) << 16);
    *(uint2*)(oute + (size_t)(c0 + c) * R + r0 + tc * 4) = make_uint2(u0, u1);
  }
}

// =============== 8-phase grouped BT GEMM, 256x256 tile, BK=64, 8 waves ========
// LDS: row-major [256][64] bf16, XOR-swizzled 16B k-octets (r4-proven layout):
// unit(16B) = row*8 + (koct ^ (row&7)).  Staging dest linear in tid; global
// source pre-swizzled within each row's 128B line (coalesced).  ds_read_b128
// fragments 2-way bank use.  vmcnt(10) end-p1, vmcnt(8) end-p3, never 0.
// sched_barrier(0) fences around each s_barrier pin the phase skeleton
// (r4=184us with fences vs r5=237us without: fences are load-bearing).
#define BAR() do { __builtin_amdgcn_sched_barrier(0); \
                   __builtin_amdgcn_s_barrier(); \
                   __builtin_amdgcn_sched_barrier(0); } while (0)

#define STG(gbase, kt, lbuf, c) \
  async16((gbase) + (size_t)((c) * 64 + srcRow) * Kstr + (kt) + srcK8, \
          (lbuf) + (c) * 4096 + tid * 8)

#define LDU(buf, row, koct) \
  (*(const bf16x8*)((buf) + (((row) * 8 + ((koct) ^ ((row) & 7))) * 8)))

#define LDA4(P) \
  const int ar0 = wm * 128 + (P) * 32 + lr; \
  bf16x8 aA = LDU(lAc, ar0, klane); \
  bf16x8 aB = LDU(lAc, ar0, 4 + klane); \
  bf16x8 aC = LDU(lAc, ar0 + 16, klane); \
  bf16x8 aD = LDU(lAc, ar0 + 16, 4 + klane);

#define PHASE_MFMA(M0, M1) \
  __builtin_amdgcn_s_setprio(1); \
  _Pragma("unroll") \
  for (int n = 0; n < 4; n++) { \
    acc[M0][n] = __builtin_amdgcn_mfma_f32_16x16x32_bf16(aA, b[n][0], acc[M0][n], 0, 0, 0); \
    acc[M0][n] = __builtin_amdgcn_mfma_f32_16x16x32_bf16(aB, b[n][1], acc[M0][n], 0, 0, 0); \
    acc[M1][n] = __builtin_amdgcn_mfma_f32_16x16x32_bf16(aC, b[n][0], acc[M1][n], 0, 0, 0); \
    acc[M1][n] = __builtin_amdgcn_mfma_f32_16x16x32_bf16(aD, b[n][1], acc[M1][n], 0, 0, 0); \
  } \
  __builtin_amdgcn_s_setprio(0);

template <bool RELU, bool OUTF32>
__global__ __launch_bounds__(512, 2) void gemm8_k(
    const int* __restrict__ ctrl, const unsigned short* __restrict__ A,
    const unsigned short* __restrict__ Bw, const float* __restrict__ bias,
    void* __restrict__ Cout, int Kstr, int N) {
  __shared__ unsigned short lds[65536];   // 128 KiB: A 2x32KB | B 2x32KB
  // XCD-bijective block swizzle (m204): consecutive remapped blocks share
  // A-panels (same rt) and land on one XCD's L2.
  const int nx = gridDim.x;
  const int nwg = nx * gridDim.y;
  const int lin = blockIdx.y * nx + blockIdx.x;
  const int qq = nwg >> 3, r8 = nwg & 7;
  const int xcd = lin & 7, sidx = lin >> 3;
  const int wg = (xcd < r8 ? xcd * (qq + 1) : r8 * (qq + 1) + (xcd - r8) * qq) + sidx;
  const int bx = wg % nx, rt = wg / nx;
  if (rt >= ctrl[25]) return;
  const int e    = ctrl[32 + 2 * rt];
  const int row0 = ctrl[33 + 2 * rt];
  const unsigned short* Ae = A + (size_t)row0 * Kstr;
  const unsigned short* Be = Bw + (size_t)e * ((size_t)N * Kstr) + (size_t)bx * 256 * Kstr;
  unsigned short* lA = lds;
  unsigned short* lB = lds + 32768;
  const int tid = threadIdx.x, lane = tid & 63;
  const int wid = tid >> 6, wm = wid >> 2, wn = wid & 3;
  const int lr = lane & 15, klane = lane >> 4;
  const int srcRow = tid >> 3;                         // 0..63 within chunk
  const int srcK8  = ((tid & 7) ^ (srcRow & 7)) * 8;   // pre-swizzled k-octet
  const int NT = Kstr >> 6;

  f32x4 acc[8][4];
  f32x4 zero4 = {0.f, 0.f, 0.f, 0.f};
#pragma unroll
  for (int m = 0; m < 8; m++)
#pragma unroll
    for (int n = 0; n < 4; n++) acc[m][n] = zero4;

  // prologue: tile0 full (8), tile1 partial (B0-3, A0, A2)
  {
    STG(Ae, 0, lA, 0); STG(Ae, 0, lA, 1); STG(Ae, 0, lA, 2); STG(Ae, 0, lA, 3);
    STG(Be, 0, lB, 0); STG(Be, 0, lB, 1); STG(Be, 0, lB, 2); STG(Be, 0, lB, 3);
    STG(Be, 64, lB + 16384, 0); STG(Be, 64, lB + 16384, 1);
    STG(Be, 64, lB + 16384, 2); STG(Be, 64, lB + 16384, 3);
    STG(Ae, 64, lA + 16384, 0); STG(Ae, 64, lA + 16384, 2);
    asm volatile("s_waitcnt vmcnt(6)" ::: "memory");
    BAR();
  }

  for (int t = 0; t < NT; t++) {
    const int cur = t & 1;
    unsigned short* lAc = lA + cur * 16384;
    unsigned short* lBc = lB + cur * 16384;
    unsigned short* lAn = lA + (cur ^ 1) * 16384;
    const int kt1 = min(t + 1, NT - 1) * 64;
    const int kt2 = min(t + 2, NT - 1) * 64;
    bf16x8 b[4][2];
    { // ---- phase 0: read B whole + A rows 0-31; stage A chunks 1,3 of t+1
#pragma unroll
      for (int n = 0; n < 4; n++) {
        int brow = wn * 64 + n * 16 + lr;
        b[n][0] = LDU(lBc, brow, klane);
        b[n][1] = LDU(lBc, brow, 4 + klane);
      }
      LDA4(0)
      STG(Ae, kt1, lAn, 1); STG(Ae, kt1, lAn, 3);
      BAR();
      PHASE_MFMA(0, 1)
      BAR();
    }
    { // ---- phase 1: A rows 32-63; stage B chunks 0,1 of t+2; vmcnt(10)
      LDA4(1)
      STG(Be, kt2, lBc, 0); STG(Be, kt2, lBc, 1);
      BAR();
      PHASE_MFMA(2, 3)
      asm volatile("s_waitcnt vmcnt(10)" ::: "memory");
      BAR();
    }
    { // ---- phase 2: A rows 64-95; stage B chunks 2,3 of t+2
      LDA4(2)
      STG(Be, kt2, lBc, 2); STG(Be, kt2, lBc, 3);
      BAR();
      PHASE_MFMA(4, 5)
      BAR();
    }
    { // ---- phase 3: A rows 96-127; stage A chunks 0,2 of t+2; vmcnt(8)
      LDA4(3)
      STG(Ae, kt2, lAc, 0); STG(Ae, kt2, lAc, 2);
      BAR();
      PHASE_MFMA(6, 7)
      asm volatile("s_waitcnt vmcnt(8)" ::: "memory");
      BAR();
    }
  }

  // ---------------- epilogue: plain stores, no atomics -------------------------
  const int n0 = bx * 256;
  const float* be = bias + (size_t)e * N;
#pragma unroll
  for (int m = 0; m < 8; m++) {
#pragma unroll
    for (int q = 0; q < 4; q++) {
      size_t ro = (size_t)(row0 + wm * 128 + m * 16 + (lane >> 4) * 4 + q) * N;
#pragma unroll
      for (int n = 0; n < 4; n++) {
        int col = n0 + wn * 64 + n * 16 + lr;
        float v = acc[m][n][q] + be[col];
        if (RELU) v = fmaxf(v, 0.f);
        if (OUTF32) ((float*)Cout)[ro + col] = v;
        else ((unsigned short*)Cout)[ro + col] = f2bf(v);
      }
    }
  }
}

// ---------------- combine: out[t] = w0*y[r0] + w1*y[r1] ----------------------
__global__ __launch_bounds__(256) void combine_k(
    const float* __restrict__ y, const int* __restrict__ row_map,
    const float* __restrict__ t2w, float* __restrict__ out) {
  int t = blockIdx.x;
  int i = threadIdx.x * 4;
  int r0 = row_map[2 * t], r1 = row_map[2 * t + 1];
  float w0 = t2w[2 * t], w1 = t2w[2 * t + 1];
  float4 a = *(const float4*)(y + (size_t)r0 * H_DIM + i);
  float4 b = *(const float4*)(y + (size_t)r1 * H_DIM + i);
  float4 o;
  o.x = w0 * a.x + w1 * b.x;
  o.y = w0 * a.y + w1 * b.y;
  o.z = w0 * a.z + w1 * b.z;
  o.w = w0 * a.w + w1 * b.w;
  *(float4*)(out + (size_t)t * H_DIM + i) = o;
}

extern "C" void kernel_launch(void* const* d_in, const int* in_sizes, int n_in,
                              void* d_out, int out_size, void* d_ws, size_t ws_size,
                              hipStream_t stream) {
  const float* x  = (const float*)d_in[0];
  const float* Wr = (const float*)d_in[1];
  const float* br = (const float*)d_in[2];
  const float* W1 = (const float*)d_in[3];
  const float* b1 = (const float*)d_in[4];
  const float* W2 = (const float*)d_in[5];
  const float* b2 = (const float*)d_in[6];
  float* out = (float*)d_out;

  char* ws = (char*)d_ws;
  int*   ctrl    = (int*)ws;                       // counts/offs/cursors/tile table
  int*   t2i     = (int*)(ws + 4096);
  float* t2w     = (float*)(ws + 4096 + 32768);
  int*   row_map = (int*)(ws + 4096 + 65536);      // R_CAP ints
  size_t off = (size_t)1 << 20;
  unsigned short* WT1 = (unsigned short*)(ws + off); off += (size_t)E_NUM * F_DIM * H_DIM * 2;
  unsigned short* WT2 = (unsigned short*)(ws + off); off += (size_t)E_NUM * H_DIM * F_DIM * 2;
  unsigned short* xg  = (unsigned short*)(ws + off); off += (size_t)R_CAP * H_DIM * 2;
  unsigned short* hb  = (unsigned short*)(ws + off); off += (size_t)R_CAP * F_DIM * 2;
  float*          yb  = (float*)(ws + off);          off += (size_t)R_CAP * H_DIM * 4;

  if (ws_size < off) {  // not enough scratch: fail visibly, don't corrupt memory
    hipMemsetAsync(d_out, 0, (size_t)out_size * 4, stream);
    return;
  }

  hipMemsetAsync(ctrl, 0, 4096, stream);
  hipMemsetAsync(xg, 0, (size_t)R_CAP * H_DIM * 2, stream);   // pad rows deterministic
  transpose_cvt_k<<<dim3(F_DIM / 64, H_DIM / 64, E_NUM), 256, 0, stream>>>(W1, WT1, H_DIM, F_DIM);
  transpose_cvt_k<<<dim3(H_DIM / 64, F_DIM / 64, E_NUM), 256, 0, stream>>>(W2, WT2, F_DIM, H_DIM);
  router_k<<<dim3(T_TOK / 4), 256, 0, stream>>>(x, Wr, br, ctrl, t2i, t2w);
  scan_k<<<dim3(1), 64, 0, stream>>>(ctrl);
  gather_k<<<dim3(R_TOT), 128, 0, stream>>>(x, t2i, ctrl, row_map, xg);
  // GEMM1: hb = relu(xg @ W1 + b1), bf16   [rows x F]
  gemm8_k<true, false><<<dim3(F_DIM / 256, 39), 512, 0, stream>>>(
      ctrl, xg, WT1, b1, hb, H_DIM, F_DIM);
  // GEMM2: yb = hb @ W2 + b2, fp32         [rows x H]
  gemm8_k<false, true><<<dim3(H_DIM / 256, 39), 512, 0, stream>>>(
      ctrl, hb, WT2, b2, yb, F_DIM, H_DIM);
  combine_k<<<dim3(T_TOK), 256, 0, stream>>>(yb, row_map, t2w, out);
}